// Round 2
// baseline (543.461 us; speedup 1.0000x reference)
//
#include <hip/hip_runtime.h>
#include <hip/hip_bf16.h>

// Problem constants (from reference): B=32, HQ=32, HKV=8, D=128, T=2048
#define NB 32
#define NHQ 32
#define NHKV 8
#define GQ 4          // HQ / HKV
#define DD 128
#define TT 2048
#define NSPLIT 8
#define CHUNK 256     // TT / NSPLIT
#define PSLD 260      // padded ps stride (260 % 32 = 4 -> spreads 4 heads over banks)

__device__ __forceinline__ float warp_max(float v) {
#pragma unroll
    for (int o = 32; o >= 1; o >>= 1) v = fmaxf(v, __shfl_xor(v, o));
    return v;
}
__device__ __forceinline__ float warp_sum(float v) {
#pragma unroll
    for (int o = 32; o >= 1; o >>= 1) v += __shfl_xor(v, o);
    return v;
}
// tanh(x) = 1 - 2/(e^{2x}+1); saturates to +-1 for large |x| (inf-safe)
__device__ __forceinline__ float fast_tanh(float x) {
    const float e = __expf(2.0f * x);
    return 1.0f - 2.0f / (e + 1.0f);
}

// Pass 1: per (split, kv_head, batch) partial flash-attention over a 256-token chunk.
__global__ __launch_bounds__(256) void attn_part_kernel(
    const float* __restrict__ q,       // [B, HQ*D]
    const float* __restrict__ knew,    // [B, HKV*D]
    const float* __restrict__ vnew,    // [B, HKV*D]
    const float* __restrict__ kbuf,    // [POOL, HKV, D]
    const float* __restrict__ vbuf,    // [POOL, HKV, D]
    const int* __restrict__ req_to_token,     // [B, T]
    const int* __restrict__ req_pool_indices, // [B]
    const int* __restrict__ seq_lens,         // [B]
    const int* __restrict__ out_cache_loc,    // [B]
    float* __restrict__ part_o,   // [B][HKV][GQ][NSPLIT][D]
    float* __restrict__ part_ml)  // [B][HKV][GQ][NSPLIT][2]
{
    const int tid   = threadIdx.x;
    const int split = blockIdx.x;
    const int kv    = blockIdx.y;
    const int b     = blockIdx.z;

    const int sl = seq_lens[b];
    const int t0 = split * CHUNK;
    const int nt = min(sl - t0, CHUNK);   // tokens in this chunk (may be <=0)

    float* po  = part_o  + (((size_t)b * NHKV + kv) * GQ) * NSPLIT * DD;
    float* pml = part_ml + (((size_t)b * NHKV + kv) * GQ) * NSPLIT * 2;

    if (nt <= 0) {
        for (int i = tid; i < GQ * DD; i += 256) {
            const int g = i >> 7, d = i & 127;
            po[(g * NSPLIT + split) * DD + d] = 0.f;
        }
        if (tid < GQ) {
            pml[(tid * NSPLIT + split) * 2 + 0] = -1e30f;
            pml[(tid * NSPLIT + split) * 2 + 1] = 0.f;
        }
        return;
    }

    __shared__ __align__(16) float qs[GQ][DD];       // 2 KB
    __shared__ float ps[GQ][PSLD];                   // ~4 KB (scores -> probs)
    __shared__ int   slot_s[CHUNK];                  // 1 KB
    __shared__ float redm[GQ][4];
    __shared__ float msh[GQ], lsh[GQ];
    __shared__ __align__(16) float opart[4][GQ][DD]; // 8 KB

    // q for the 4 grouped heads: q.reshape(B, HKV, GQ, D)
    const float* qb = q + ((size_t)b * NHQ + kv * GQ) * DD;
    for (int i = tid; i < GQ * DD; i += 256) qs[i >> 7][i & 127] = qb[i];
    const int req = req_pool_indices[b];
    const int ocl = out_cache_loc[b];
    slot_s[tid] = req_to_token[(size_t)req * TT + t0 + tid];  // coalesced
    __syncthreads();

    const int lane = tid & 63, w = tid >> 6;
    const float* knewrow = knew + ((size_t)b * NHKV + kv) * DD;
    const float* vnewrow = vnew + ((size_t)b * NHKV + kv) * DD;

    constexpr float SCALING   = 0.08838834764831845f;
    constexpr float LOGIT_CAP = 30.0f;
    const float cmul = SCALING / LOGIT_CAP;

    // ---- score phase: 4 lanes per token, 16B/lane coalesced K reads ----
    const int a = lane & 3;        // dim-group within token
    float wm0 = -1e30f, wm1 = -1e30f, wm2 = -1e30f, wm3 = -1e30f;
    for (int p = 0; p < 4; ++p) {
        const int tg   = (w << 6) + (p << 4) + (lane >> 2);
        const int slot = slot_s[tg];
        const float* krow = (slot == ocl)
            ? knewrow : (kbuf + ((size_t)slot * NHKV + kv) * DD);
        float d0 = 0.f, d1 = 0.f, d2 = 0.f, d3 = 0.f;
#pragma unroll
        for (int kk = 0; kk < 8; ++kk) {
            const int off = kk * 16 + a * 4;   // 4 lanes cover one 64B line
            const float4 kk4 = *(const float4*)(krow + off);
            const float4 q0 = *(const float4*)(&qs[0][off]);
            const float4 q1 = *(const float4*)(&qs[1][off]);
            const float4 q2 = *(const float4*)(&qs[2][off]);
            const float4 q3 = *(const float4*)(&qs[3][off]);
            d0 += kk4.x * q0.x + kk4.y * q0.y + kk4.z * q0.z + kk4.w * q0.w;
            d1 += kk4.x * q1.x + kk4.y * q1.y + kk4.z * q1.z + kk4.w * q1.w;
            d2 += kk4.x * q2.x + kk4.y * q2.y + kk4.z * q2.z + kk4.w * q2.w;
            d3 += kk4.x * q3.x + kk4.y * q3.y + kk4.z * q3.z + kk4.w * q3.w;
        }
        // fold the 4-lane dim groups
        d0 += __shfl_xor(d0, 1); d0 += __shfl_xor(d0, 2);
        d1 += __shfl_xor(d1, 1); d1 += __shfl_xor(d1, 2);
        d2 += __shfl_xor(d2, 1); d2 += __shfl_xor(d2, 2);
        d3 += __shfl_xor(d3, 1); d3 += __shfl_xor(d3, 2);
        float s0 = LOGIT_CAP * fast_tanh(d0 * cmul);
        float s1 = LOGIT_CAP * fast_tanh(d1 * cmul);
        float s2 = LOGIT_CAP * fast_tanh(d2 * cmul);
        float s3 = LOGIT_CAP * fast_tanh(d3 * cmul);
        if (tg >= nt) { s0 = s1 = s2 = s3 = -1e30f; }
        wm0 = fmaxf(wm0, s0); wm1 = fmaxf(wm1, s1);
        wm2 = fmaxf(wm2, s2); wm3 = fmaxf(wm3, s3);
        // lane a writes head a's score for its token
        const float sa = (a == 0) ? s0 : (a == 1) ? s1 : (a == 2) ? s2 : s3;
        ps[a][tg] = sa;
    }
    // block max per head
    wm0 = warp_max(wm0); wm1 = warp_max(wm1);
    wm2 = warp_max(wm2); wm3 = warp_max(wm3);
    if (lane == 0) {
        redm[0][w] = wm0; redm[1][w] = wm1; redm[2][w] = wm2; redm[3][w] = wm3;
    }
    __syncthreads();
    if (tid < GQ) {
        const float* r = redm[tid];
        msh[tid] = fmaxf(fmaxf(r[0], r[1]), fmaxf(r[2], r[3]));
    }
    __syncthreads();

    // ---- exp + block sum per head (thread = token) ----
    {
        const float m0 = msh[0], m1 = msh[1], m2 = msh[2], m3 = msh[3];
        const bool valid = tid < nt;
        float p0 = valid ? __expf(ps[0][tid] - m0) : 0.f;
        float p1 = valid ? __expf(ps[1][tid] - m1) : 0.f;
        float p2 = valid ? __expf(ps[2][tid] - m2) : 0.f;
        float p3 = valid ? __expf(ps[3][tid] - m3) : 0.f;
        ps[0][tid] = p0; ps[1][tid] = p1; ps[2][tid] = p2; ps[3][tid] = p3;
        p0 = warp_sum(p0); p1 = warp_sum(p1); p2 = warp_sum(p2); p3 = warp_sum(p3);
        if (lane == 0) {
            redm[0][w] = p0; redm[1][w] = p1; redm[2][w] = p2; redm[3][w] = p3;
        }
    }
    __syncthreads();
    if (tid < GQ) {
        const float* r = redm[tid];
        lsh[tid] = r[0] + r[1] + r[2] + r[3];
    }

    // ---- PV phase: half-wave token streams, float4/lane V reads ----
    {
        const int hs = tid >> 5;          // 0..7 token stream
        const int dl = (tid & 31) << 2;   // 4 dims per lane
        float4 a0 = {0,0,0,0}, a1 = {0,0,0,0}, a2 = {0,0,0,0}, a3 = {0,0,0,0};
        for (int t = hs; t < nt; t += 8) {
            const int slot = slot_s[t];
            const float* vrow = (slot == ocl)
                ? vnewrow : (vbuf + ((size_t)slot * NHKV + kv) * DD);
            const float4 vv = *(const float4*)(vrow + dl);
            const float p0 = ps[0][t], p1 = ps[1][t], p2 = ps[2][t], p3 = ps[3][t];
            a0.x += p0 * vv.x; a0.y += p0 * vv.y; a0.z += p0 * vv.z; a0.w += p0 * vv.w;
            a1.x += p1 * vv.x; a1.y += p1 * vv.y; a1.z += p1 * vv.z; a1.w += p1 * vv.w;
            a2.x += p2 * vv.x; a2.y += p2 * vv.y; a2.z += p2 * vv.z; a2.w += p2 * vv.w;
            a3.x += p3 * vv.x; a3.y += p3 * vv.y; a3.z += p3 * vv.z; a3.w += p3 * vv.w;
        }
        // fold the two half-wave streams (lane l and l^32 hold same dims)
        a0.x += __shfl_xor(a0.x, 32); a0.y += __shfl_xor(a0.y, 32);
        a0.z += __shfl_xor(a0.z, 32); a0.w += __shfl_xor(a0.w, 32);
        a1.x += __shfl_xor(a1.x, 32); a1.y += __shfl_xor(a1.y, 32);
        a1.z += __shfl_xor(a1.z, 32); a1.w += __shfl_xor(a1.w, 32);
        a2.x += __shfl_xor(a2.x, 32); a2.y += __shfl_xor(a2.y, 32);
        a2.z += __shfl_xor(a2.z, 32); a2.w += __shfl_xor(a2.w, 32);
        a3.x += __shfl_xor(a3.x, 32); a3.y += __shfl_xor(a3.y, 32);
        a3.z += __shfl_xor(a3.z, 32); a3.w += __shfl_xor(a3.w, 32);
        if ((tid & 32) == 0) {
            *(float4*)&opart[w][0][dl] = a0;
            *(float4*)&opart[w][1][dl] = a1;
            *(float4*)&opart[w][2][dl] = a2;
            *(float4*)&opart[w][3][dl] = a3;
        }
    }
    __syncthreads();
    // cross-wave reduce + store partials
    for (int i = tid; i < GQ * DD; i += 256) {
        const int g = i >> 7, d = i & 127;
        const float s = opart[0][g][d] + opart[1][g][d] + opart[2][g][d] + opart[3][g][d];
        po[(g * NSPLIT + split) * DD + d] = s;
    }
    if (tid < GQ) {
        pml[(tid * NSPLIT + split) * 2 + 0] = msh[tid];
        pml[(tid * NSPLIT + split) * 2 + 1] = lsh[tid];
    }
}

// Pass 2: combine NSPLIT partials per (b, hq) head.
__global__ __launch_bounds__(128) void attn_combine_kernel(
    const float* __restrict__ part_o,   // [B][HKV][GQ][NSPLIT][D]
    const float* __restrict__ part_ml,  // [B][HKV][GQ][NSPLIT][2]
    float* __restrict__ out)            // [B, HQ*D]
{
    const int h  = blockIdx.x;        // 0 .. B*HQ-1
    const int d  = threadIdx.x;       // 0 .. 127
    const int b  = h >> 5;            // / HQ
    const int hq = h & 31;            // kv*GQ + g

    const float* ml = part_ml + ((size_t)b * NHKV * GQ + hq) * NSPLIT * 2;
    float M = -1e30f;
#pragma unroll
    for (int s = 0; s < NSPLIT; s++) M = fmaxf(M, ml[s * 2]);
    float L = 0.f;
#pragma unroll
    for (int s = 0; s < NSPLIT; s++) L += ml[s * 2 + 1] * __expf(ml[s * 2] - M);

    const float* po = part_o + ((size_t)b * NHKV * GQ + hq) * NSPLIT * DD;
    float acc = 0.f;
#pragma unroll
    for (int s = 0; s < NSPLIT; s++) acc += po[s * DD + d] * __expf(ml[s * 2] - M);

    out[((size_t)b * NHQ + hq) * DD + d] = acc / L;
}

extern "C" void kernel_launch(void* const* d_in, const int* in_sizes, int n_in,
                              void* d_out, int out_size, void* d_ws, size_t ws_size,
                              hipStream_t stream) {
    (void)in_sizes; (void)n_in; (void)out_size; (void)ws_size;
    const float* q    = (const float*)d_in[0];
    const float* k    = (const float*)d_in[1];
    const float* v    = (const float*)d_in[2];
    const float* kbuf = (const float*)d_in[3];
    const float* vbuf = (const float*)d_in[4];
    const int* req_to_token     = (const int*)d_in[5];
    const int* req_pool_indices = (const int*)d_in[6];
    const int* seq_lens         = (const int*)d_in[7];
    const int* out_cache_loc    = (const int*)d_in[8];
    float* out = (float*)d_out;

    float* part_o  = (float*)d_ws;                                  // 4 MB
    float* part_ml = part_o + (size_t)NB * NHKV * GQ * NSPLIT * DD; // 64 KB

    dim3 g1(NSPLIT, NHKV, NB), b1(256);
    attn_part_kernel<<<g1, b1, 0, stream>>>(q, k, v, kbuf, vbuf,
        req_to_token, req_pool_indices, seq_lens, out_cache_loc,
        part_o, part_ml);

    dim3 g2(NB * NHQ), b2(128);
    attn_combine_kernel<<<g2, b2, 0, stream>>>(part_o, part_ml, out);
}